// Round 6
// baseline (133.461 us; speedup 1.0000x reference)
//
#include <hip/hip_runtime.h>
#include <hip/hip_bf16.h>
#include <math.h>

// Problem constants (fixed by setup_inputs): B=4, N=4096, Fin=Fout=64
#define BB 4
#define NN 4096
#define FF 64
#define KS (NN / 32)           // 128 K-step blocks (32 j's each)
#define NKW (KS / 4)           // 32 K-steps per wave (4 waves, full K per block)
#define C0F 3.35462628e-4f     // exp(-8)  (global softmax shift, cancels on normalize)
#define C1F 3.35462628e-6f     // 0.01 * exp(-8)
#define PREB 512               // pre-path blocks (BB*NN/32); pack blocks follow

typedef _Float16 half8 __attribute__((ext_vector_type(8)));
typedef float f32x4 __attribute__((ext_vector_type(4)));

// ---------------------------------------------------------------------------
// K1 (fused): blocks [0, PREB) run the Xw/LE/RE pre path; blocks [PREB, ...)
// stream-pack the mask bits. Grid-fusion hides pre's ~4 us of LDS-heavy
// compute under pack's HBM streaming (pack blocks use zero LDS).
//
// Pack path: each lane reads uint4 (4 cols, 16 B/lane), packs a 4-bit
// nibble, OR-combines across aligned 8-lane groups via 3x shfl_xor,
// 1 writer/8 lanes. bitsT[word][row], word = col>>5, bit = col&31.
// Diagonal injected where c4 == row>>2.
//
// Pre path: Xw = X @ W in fp32, emitted in MFMA B-fragment-packed fp16:
//   XwP[b][ks][ct][lane=q*16+n][jj] = Xw[b][j = ks*32 + q*8 + jj][f = ct*16+n]
// Row-softmax precursors fully precomputed here (once per row):
//   LE=(lc=l*C1, el=exp(l-8)), ERt=exp(r), RCt=r*C1+C0.
__global__ __launch_bounds__(256, 2)
void k_prep(const float* __restrict__ X, const float* __restrict__ W,
            const float* __restrict__ avec, const int* __restrict__ A,
            _Float16* __restrict__ XwP, float2* __restrict__ LE,
            float* __restrict__ ERt, float* __restrict__ RCt,
            unsigned int* __restrict__ bitsT) {
    __shared__ __align__(16) float Wl[64 * 64];
    __shared__ __align__(16) float Xl[32][64];
    __shared__ __align__(16) float T[32][65];
    __shared__ float al[64];
    __shared__ float ar[64];

    const int t = threadIdx.x;

    if (blockIdx.x >= PREB) {
        // ---- pack path: 16384 blocks x 256 lanes x 4 cols = 16M cells ----
        int pidx = (blockIdx.x - PREB) * 256 + t;
        int row  = pidx >> 10;          // 1024 uint4 per row
        int c4   = pidx & 1023;
        const uint4* A4 = (const uint4*)A;
        uint4 av = A4[pidx];
        unsigned int nib = 0;
        nib |= ((int)av.x > 0) ? 1u : 0u;
        nib |= ((int)av.y > 0) ? 2u : 0u;
        nib |= ((int)av.z > 0) ? 4u : 0u;
        nib |= ((int)av.w > 0) ? 8u : 0u;
        if (c4 == (row >> 2)) nib |= 1u << (row & 3);   // diagonal
        int lane = t & 63;
        unsigned int v = nib << ((lane & 7) * 4);
        v |= __shfl_xor(v, 1);
        v |= __shfl_xor(v, 2);
        v |= __shfl_xor(v, 4);
        if ((lane & 7) == 0)
            bitsT[(size_t)(c4 >> 3) * NN + row] = v;
        return;
    }

    // ---- pre path (blocks 0..PREB-1) ----
    const int lane = t & 63;
    const int wv = t >> 6;
    const int r0 = blockIdx.x * 32;          // global row base (b*NN + jn)

    #pragma unroll
    for (int k = 0; k < 16; ++k) Wl[t + k * 256] = W[t + k * 256];
    if (t < 64) { al[t] = avec[t]; ar[t] = avec[64 + t]; }
    {   // stage X tile: 32 rows x 64 = 512 float4
        const float4* xs = (const float4*)(X + (size_t)r0 * 64);
        float4* xd = (float4*)&Xl[0][0];
        xd[t] = xs[t];
        xd[t + 256] = xs[t + 256];
    }
    __syncthreads();

    float Wreg[64];                          // this lane's W column (f = lane)
    #pragma unroll
    for (int k = 0; k < 64; ++k) Wreg[k] = Wl[k * 64 + lane];

    #pragma unroll
    for (int rr = 0; rr < 8; ++rr) {
        int lrow = wv * 8 + rr;
        int row  = r0 + lrow;
        float a0 = 0.f, a1 = 0.f, a2 = 0.f, a3 = 0.f;
        #pragma unroll
        for (int k = 0; k < 64; k += 4) {
            float4 x = *(const float4*)&Xl[lrow][k];   // broadcast read
            a0 = fmaf(x.x, Wreg[k],     a0);
            a1 = fmaf(x.y, Wreg[k + 1], a1);
            a2 = fmaf(x.z, Wreg[k + 2], a2);
            a3 = fmaf(x.w, Wreg[k + 3], a3);
        }
        float acc = (a0 + a1) + (a2 + a3);
        T[lrow][lane] = acc;

        float lv = acc * al[lane];
        float rv = acc * ar[lane];
        #pragma unroll
        for (int off = 32; off; off >>= 1) {
            lv += __shfl_xor(lv, off, 64);
            rv += __shfl_xor(rv, off, 64);
        }
        if (lane == 0) {
            LE[row]  = make_float2(lv * C1F, __expf(lv - 8.f));
            ERt[row] = __expf(rv);
            RCt[row] = fmaf(rv, C1F, C0F);
        }
    }
    __syncthreads();

    // packed store: thread t -> [ct = t>>6][lane][jj=0..7]
    int b  = r0 >> 12;
    int ks = (r0 & (NN - 1)) >> 5;
    int ct = t >> 6;
    int q  = lane >> 4, n = lane & 15;
    half8 h;
    #pragma unroll
    for (int jj = 0; jj < 8; ++jj)
        h[jj] = (_Float16)T[q * 8 + jj][ct * 16 + n];
    *(half8*)&XwP[((((size_t)b * KS + ks) * 4 + ct) * 64 + lane) * 8] = h;
}

// ---------------------------------------------------------------------------
// K3: flash pass. R17: 64 i-rows per block (was 32). Rationale: k_main is
// L2-BW-bound -- 512 blocks x 512 KB XwP slice = 256 MB L2 @ ~34.5 TB/s
// = 7.4 us, matching the measured k_main time; VALU floor is only ~4.8 us.
// Doubling rows/block halves XwP L2 traffic to 128 MB; total VALU+MFMA
// issue per SIMD is exactly conserved (same wave-instruction count, half
// the loads per CU). Grid 64 x 4 = 256 blocks = 1 block/CU = 1 wave/SIMD:
//  - __launch_bounds__(256,1) -> 512-VGPR budget vs ~170 live: NO spill
//    possible (R15's failure was the 128-cap, not the row count).
//  - latency: 1-deep prefetch spans the ~2x body (~800 cy >> ~200 cy L2);
//    unroll 2 keeps the same scheduling window as R16's unroll 4.
//  - setprio dropped: nothing to arbitrate at 1 wave/SIMD.
// K-quarter split and combine-tree pairing unchanged -> every row's
// accumulation order is bitwise identical to R16.
// P math: p = mask * max(el*er_j, lc + rc_j), LUT masks, cvt_pkrtz.
__global__ __launch_bounds__(256, 1)
void k_main(const _Float16* __restrict__ XwP, const float2* __restrict__ LE,
            const float* __restrict__ ERt, const float* __restrict__ RCt,
            const unsigned int* __restrict__ bitsT, float* __restrict__ out) {
    __shared__ __align__(16) char smem[35840];
    __shared__ uint2 lutm[16];
    float* REs_er = (float*)smem;                       // [0,16384): er_j (K-loop)
    float* REs_rc = (float*)(smem + 16384);             // [16384,32768): rc_j
    float (*Lacc)[64][68] = (float (*)[64][68])smem;    // [0, 34816) after K-loop
    float* Lsum = (float*)(smem + 34816);               // [34816, 35328)

    const int t  = threadIdx.x;
    const int b  = blockIdx.y;
    const int i0 = blockIdx.x * 64;

    const int lane = t & 63;
    const int wv   = t >> 6;            // K-quarter
    const int lm   = lane & 15;
    const int q    = lane >> 4;

    // 4 row-groups: rows i0 + g*16 + lm
    int rowg[4];
    float2 le[4];                       // (lc, el) per group
    #pragma unroll
    for (int g = 0; g < 4; ++g) {
        rowg[g] = i0 + g * 16 + lm;
        le[g]   = LE[b * NN + rowg[g]];
    }
    const _Float16* xp = XwP + (size_t)b * KS * 2048 + (size_t)lane * 8;

    // mask-expansion LUT: nibble -> two dwords of 16-bit AND masks
    if (t < 16)
        lutm[t] = make_uint2(((t & 1) ? 0xFFFFu : 0u) | ((t & 2) ? 0xFFFF0000u : 0u),
                             ((t & 4) ? 0xFFFFu : 0u) | ((t & 8) ? 0xFFFF0000u : 0u));

    // stage er/rc for batch b: straight float4 copies, conflict-free
    {
        const float4* es = (const float4*)(ERt + (size_t)b * NN);
        const float4* cs = (const float4*)(RCt + (size_t)b * NN);
        float4* ed = (float4*)REs_er;
        float4* cd = (float4*)REs_rc;
        #pragma unroll
        for (int k = 0; k < 4; ++k) {
            ed[t + k * 256] = es[t + k * 256];
            cd[t + k * 256] = cs[t + k * 256];
        }
    }
    __syncthreads();

    f32x4 acc[4][4];                    // [group][ct]
    f32x4 sacc[4];
    #pragma unroll
    for (int g = 0; g < 4; ++g) {
        sacc[g] = (f32x4)0.f;
        #pragma unroll
        for (int ct = 0; ct < 4; ++ct) acc[g][ct] = (f32x4)0.f;
    }
    half8 vones;
    #pragma unroll
    for (int k = 0; k < 8; ++k) vones[k] = (_Float16)1.0f;

    const int ks0 = wv * NKW;            // this wave's 32 K-steps

    // prefetch step 0
    const _Float16* base = xp + (size_t)ks0 * 2048;
    half8 nb0 = *(const half8*)(base + 0 * 512);
    half8 nb1 = *(const half8*)(base + 1 * 512);
    half8 nb2 = *(const half8*)(base + 2 * 512);
    half8 nb3 = *(const half8*)(base + 3 * 512);
    unsigned int nw[4];
    #pragma unroll
    for (int g = 0; g < 4; ++g) nw[g] = bitsT[(size_t)ks0 * NN + rowg[g]];

    #pragma unroll 2
    for (int kk = 0; kk < NKW; ++kk) {
        half8 bf0 = nb0, bf1 = nb1, bf2 = nb2, bf3 = nb3;
        unsigned int wx[4];
        #pragma unroll
        for (int g = 0; g < 4; ++g) wx[g] = nw[g] >> (q * 8);

        // prefetch next step (clamped re-read on the last iteration)
        {
            int nk = kk + 1 < NKW ? kk + 1 : kk;
            const _Float16* nbase = xp + (size_t)(ks0 + nk) * 2048;
            nb0 = *(const half8*)(nbase + 0 * 512);
            nb1 = *(const half8*)(nbase + 1 * 512);
            nb2 = *(const half8*)(nbase + 2 * 512);
            nb3 = *(const half8*)(nbase + 3 * 512);
            #pragma unroll
            for (int g = 0; g < 4; ++g)
                nw[g] = bitsT[(size_t)(ks0 + nk) * NN + rowg[g]];
        }

        // r-side: er and rc float4 pairs (broadcast within quad, conflict-free),
        // shared by all 4 row-groups
        const float4* ep = (const float4*)(REs_er + (ks0 + kk) * 32 + q * 8);
        float4 e0v = ep[0], e1v = ep[1];
        const float4* cp = (const float4*)(REs_rc + (ks0 + kk) * 32 + q * 8);
        float4 c0v = cp[0], c1v = cp[1];
        float er8[8] = {e0v.x, e0v.y, e0v.z, e0v.w, e1v.x, e1v.y, e1v.z, e1v.w};
        float rc8[8] = {c0v.x, c0v.y, c0v.z, c0v.w, c1v.x, c1v.y, c1v.z, c1v.w};

        // per group: p = max(el*er_j, lc + rc_j); pack f16 (RTZ); AND-mask; 5 MFMA
        #pragma unroll
        for (int g = 0; g < 4; ++g) {
            uint2 m0 = lutm[wx[g] & 15], m1 = lutm[(wx[g] >> 4) & 15];
            float p[8];
            #pragma unroll
            for (int jj = 0; jj < 8; ++jj)
                p[jj] = fmaxf(le[g].y * er8[jj], le[g].x + rc8[jj]);
            uint4 u;
            u.x = __builtin_bit_cast(unsigned int, __builtin_amdgcn_cvt_pkrtz(p[0], p[1])) & m0.x;
            u.y = __builtin_bit_cast(unsigned int, __builtin_amdgcn_cvt_pkrtz(p[2], p[3])) & m0.y;
            u.z = __builtin_bit_cast(unsigned int, __builtin_amdgcn_cvt_pkrtz(p[4], p[5])) & m1.x;
            u.w = __builtin_bit_cast(unsigned int, __builtin_amdgcn_cvt_pkrtz(p[6], p[7])) & m1.y;
            half8 af = __builtin_bit_cast(half8, u);

            acc[g][0] = __builtin_amdgcn_mfma_f32_16x16x32_f16(af, bf0, acc[g][0], 0, 0, 0);
            acc[g][1] = __builtin_amdgcn_mfma_f32_16x16x32_f16(af, bf1, acc[g][1], 0, 0, 0);
            acc[g][2] = __builtin_amdgcn_mfma_f32_16x16x32_f16(af, bf2, acc[g][2], 0, 0, 0);
            acc[g][3] = __builtin_amdgcn_mfma_f32_16x16x32_f16(af, bf3, acc[g][3], 0, 0, 0);
            sacc[g]   = __builtin_amdgcn_mfma_f32_16x16x32_f16(af, vones, sacc[g], 0, 0, 0);
        }
    }

    __syncthreads();   // all waves done reading REs before Lacc overlays it

    // stage 1: waves 2,3 dump  (D[row = q*4+r][col = lm] per 16x16 tile)
    if (wv >= 2) {
        #pragma unroll
        for (int g = 0; g < 4; ++g) {
            #pragma unroll
            for (int r = 0; r < 4; ++r) {
                int lrow = g * 16 + q * 4 + r;
                #pragma unroll
                for (int ct = 0; ct < 4; ++ct)
                    Lacc[wv - 2][lrow][ct * 16 + lm] = acc[g][ct][r];
                if (lm == 0) Lsum[(wv - 2) * 64 + lrow] = sacc[g][r];
            }
        }
    }
    __syncthreads();
    // stage 2: waves 0,1 absorb + dump
    if (wv < 2) {
        #pragma unroll
        for (int g = 0; g < 4; ++g) {
            #pragma unroll
            for (int r = 0; r < 4; ++r) {
                int lrow = g * 16 + q * 4 + r;
                #pragma unroll
                for (int ct = 0; ct < 4; ++ct)
                    Lacc[wv][lrow][ct * 16 + lm] += acc[g][ct][r];
                if (lm == 0) Lsum[wv * 64 + lrow] += sacc[g][r];
            }
        }
    }
    __syncthreads();
    // stage 3: combine the 2 buffers, normalize, final coalesced write (64 rows)
    #pragma unroll
    for (int it = 0; it < 4; ++it) {
        int idx  = t + it * 256;
        int lrow = idx >> 4;            // 0..63
        int c0   = (idx & 15) * 4;      // 0..60
        float s = Lsum[lrow] + Lsum[64 + lrow];
        float inv = 1.f / s;
        float4 o;
        o.x = (Lacc[0][lrow][c0 + 0] + Lacc[1][lrow][c0 + 0]) * inv;
        o.y = (Lacc[0][lrow][c0 + 1] + Lacc[1][lrow][c0 + 1]) * inv;
        o.z = (Lacc[0][lrow][c0 + 2] + Lacc[1][lrow][c0 + 2]) * inv;
        o.w = (Lacc[0][lrow][c0 + 3] + Lacc[1][lrow][c0 + 3]) * inv;
        *(float4*)&out[((size_t)(b * NN + i0 + lrow) << 6) + c0] = o;
    }
}

// ---------------------------------------------------------------------------
extern "C" void kernel_launch(void* const* d_in, const int* in_sizes, int n_in,
                              void* d_out, int out_size, void* d_ws, size_t ws_size,
                              hipStream_t stream) {
    const float* X    = (const float*)d_in[0];
    const int*   A    = (const int*)d_in[1];
    const float* W    = (const float*)d_in[2];
    const float* avec = (const float*)d_in[3];
    float* out = (float*)d_out;

    char* ws = (char*)d_ws;
    size_t off = 0;
    _Float16* XwP = (_Float16*)(ws + off); off += (size_t)BB * NN * FF * 2;  // 2 MB
    float2* LE = (float2*)(ws + off);      off += (size_t)BB * NN * 8;       // 128 KB
    float* ERt = (float*)(ws + off);       off += (size_t)BB * NN * 4;       // 64 KB
    float* RCt = (float*)(ws + off);       off += (size_t)BB * NN * 4;       // 64 KB
    unsigned int* bitsT = (unsigned int*)(ws + off);
    off += (size_t)KS * NN * 4;                                              // 2 MB
    (void)off; (void)ws_size;

    // fused pre + pack: pre blocks first (co-resident with the pack flood)
    k_prep<<<PREB + NN * NN / 1024, 256, 0, stream>>>(X, W, avec, A, XwP, LE, ERt, RCt, bitsT);
    k_main<<<dim3(NN / 64, BB), 256, 0, stream>>>(XwP, LE, ERt, RCt, bitsT, out);
}

// Round 7
// 123.522 us; speedup vs baseline: 1.0805x; 1.0805x over previous
//
#include <hip/hip_runtime.h>
#include <hip/hip_bf16.h>
#include <math.h>

// Problem constants (fixed by setup_inputs): B=4, N=4096, Fin=Fout=64
#define BB 4
#define NN 4096
#define FF 64
#define KS (NN / 32)           // 128 K-step blocks (32 j's each)
#define NKW (KS / 4)           // 32 K-steps per wave (4 waves, full K per block)
#define C0F 3.35462628e-4f     // exp(-8)  (global softmax shift, cancels on normalize)
#define C1F 3.35462628e-6f     // 0.01 * exp(-8)
#define PREB 512               // pre-path blocks (BB*NN/32); pack blocks follow

typedef _Float16 half8 __attribute__((ext_vector_type(8)));
typedef float f32x4 __attribute__((ext_vector_type(4)));

// ---------------------------------------------------------------------------
// K1 (fused): blocks [0, PREB) run the Xw/LE/RE pre path; blocks [PREB, ...)
// stream-pack the mask bits. Grid-fusion hides pre's ~4 us of LDS-heavy
// compute under pack's HBM streaming (pack blocks use zero LDS).
//
// Pack path: each lane reads uint4 (4 cols, 16 B/lane), packs a 4-bit
// nibble, OR-combines across aligned 8-lane groups via 3x shfl_xor,
// 1 writer/8 lanes. bitsT[word][row], word = col>>5, bit = col&31.
// Diagonal injected where c4 == row>>2.
//
// Pre path: Xw = X @ W in fp32, emitted in MFMA B-fragment-packed fp16:
//   XwP[b][ks][ct][lane=q*16+n][jj] = Xw[b][j = ks*32 + q*8 + jj][f = ct*16+n]
// Row-softmax precursors fully precomputed here (once per row):
//   LE=(lc=l*C1, el=exp(l-8)), ERt=exp(r), RCt=r*C1+C0.
__global__ __launch_bounds__(256, 2)
void k_prep(const float* __restrict__ X, const float* __restrict__ W,
            const float* __restrict__ avec, const int* __restrict__ A,
            _Float16* __restrict__ XwP, float2* __restrict__ LE,
            float* __restrict__ ERt, float* __restrict__ RCt,
            unsigned int* __restrict__ bitsT) {
    __shared__ __align__(16) float Wl[64 * 64];
    __shared__ __align__(16) float Xl[32][64];
    __shared__ __align__(16) float T[32][65];
    __shared__ float al[64];
    __shared__ float ar[64];

    const int t = threadIdx.x;

    if (blockIdx.x >= PREB) {
        // ---- pack path: 16384 blocks x 256 lanes x 4 cols = 16M cells ----
        int pidx = (blockIdx.x - PREB) * 256 + t;
        int row  = pidx >> 10;          // 1024 uint4 per row
        int c4   = pidx & 1023;
        const uint4* A4 = (const uint4*)A;
        uint4 av = A4[pidx];
        unsigned int nib = 0;
        nib |= ((int)av.x > 0) ? 1u : 0u;
        nib |= ((int)av.y > 0) ? 2u : 0u;
        nib |= ((int)av.z > 0) ? 4u : 0u;
        nib |= ((int)av.w > 0) ? 8u : 0u;
        if (c4 == (row >> 2)) nib |= 1u << (row & 3);   // diagonal
        int lane = t & 63;
        unsigned int v = nib << ((lane & 7) * 4);
        v |= __shfl_xor(v, 1);
        v |= __shfl_xor(v, 2);
        v |= __shfl_xor(v, 4);
        if ((lane & 7) == 0)
            bitsT[(size_t)(c4 >> 3) * NN + row] = v;
        return;
    }

    // ---- pre path (blocks 0..PREB-1) ----
    const int lane = t & 63;
    const int wv = t >> 6;
    const int r0 = blockIdx.x * 32;          // global row base (b*NN + jn)

    #pragma unroll
    for (int k = 0; k < 16; ++k) Wl[t + k * 256] = W[t + k * 256];
    if (t < 64) { al[t] = avec[t]; ar[t] = avec[64 + t]; }
    {   // stage X tile: 32 rows x 64 = 512 float4
        const float4* xs = (const float4*)(X + (size_t)r0 * 64);
        float4* xd = (float4*)&Xl[0][0];
        xd[t] = xs[t];
        xd[t + 256] = xs[t + 256];
    }
    __syncthreads();

    float Wreg[64];                          // this lane's W column (f = lane)
    #pragma unroll
    for (int k = 0; k < 64; ++k) Wreg[k] = Wl[k * 64 + lane];

    #pragma unroll
    for (int rr = 0; rr < 8; ++rr) {
        int lrow = wv * 8 + rr;
        int row  = r0 + lrow;
        float a0 = 0.f, a1 = 0.f, a2 = 0.f, a3 = 0.f;
        #pragma unroll
        for (int k = 0; k < 64; k += 4) {
            float4 x = *(const float4*)&Xl[lrow][k];   // broadcast read
            a0 = fmaf(x.x, Wreg[k],     a0);
            a1 = fmaf(x.y, Wreg[k + 1], a1);
            a2 = fmaf(x.z, Wreg[k + 2], a2);
            a3 = fmaf(x.w, Wreg[k + 3], a3);
        }
        float acc = (a0 + a1) + (a2 + a3);
        T[lrow][lane] = acc;

        float lv = acc * al[lane];
        float rv = acc * ar[lane];
        #pragma unroll
        for (int off = 32; off; off >>= 1) {
            lv += __shfl_xor(lv, off, 64);
            rv += __shfl_xor(rv, off, 64);
        }
        if (lane == 0) {
            LE[row]  = make_float2(lv * C1F, __expf(lv - 8.f));
            ERt[row] = __expf(rv);
            RCt[row] = fmaf(rv, C1F, C0F);
        }
    }
    __syncthreads();

    // packed store: thread t -> [ct = t>>6][lane][jj=0..7]
    int b  = r0 >> 12;
    int ks = (r0 & (NN - 1)) >> 5;
    int ct = t >> 6;
    int q  = lane >> 4, n = lane & 15;
    half8 h;
    #pragma unroll
    for (int jj = 0; jj < 8; ++jj)
        h[jj] = (_Float16)T[q * 8 + jj][ct * 16 + n];
    *(half8*)&XwP[((((size_t)b * KS + ks) * 4 + ct) * 64 + lane) * 8] = h;
}

// ---------------------------------------------------------------------------
// K3: flash pass, 32 i-rows per block = R16/R5 geometry (measured best:
// 512 blocks, 2/CU, 4 waves x K-quarters). R18 post-mortem of R17 counters:
// k_main is LATENCY-bound, not BW-bound (hbm 4%, L2 ~3 TB/s << 34.5,
// VALUBusy 26%, MfmaUtil 8.5%) -- the per-step critical path runs 4x
// ds_read_b128 (er/rc, ~120cy) straight into the P-build with only 2
// waves/SIMD to cover. R18 change (ONE lever): 1-deep REGISTER prefetch of
// the er/rc LDS reads -- issue step kk+1's 4 ds_read_b128 during step kk,
// so the lgkm wait lands a full body (~400cy >> 120) before use, same as
// the existing XwP/bitsT VMEM prefetch. +32 VGPR (~150 total, no spill at
// the (256,2) 256-VGPR budget).
// P math bitwise-identical: p = mask * max(el*er_j, lc + rc_j)
__global__ __launch_bounds__(256, 2)
void k_main(const _Float16* __restrict__ XwP, const float2* __restrict__ LE,
            const float* __restrict__ ERt, const float* __restrict__ RCt,
            const unsigned int* __restrict__ bitsT, float* __restrict__ out) {
    __shared__ __align__(16) char smem[32768];
    __shared__ uint2 lutm[16];
    float* REs_er = (float*)smem;                       // [0,16384): er_j
    float* REs_rc = (float*)(smem + 16384);             // [16384,32768): rc_j
    float (*Lacc)[32][68] = (float (*)[32][68])smem;    // [0, 17408) after K-loop
    float* Lsum = (float*)(smem + 17408);               // [17408, 17664)

    const int t  = threadIdx.x;
    const int b  = blockIdx.y;
    const int i0 = blockIdx.x * 32;

    const int lane = t & 63;
    const int wv   = t >> 6;            // K-quarter
    const int lm   = lane & 15;
    const int q    = lane >> 4;

    const int rowa = i0 + lm;           // row-group A: rows [i0, i0+16)
    const int rowb = i0 + 16 + lm;      // row-group B: rows [i0+16, i0+32)
    const float2 lea = LE[b * NN + rowa];   // (lc, el)
    const float2 leb = LE[b * NN + rowb];
    const _Float16* xp = XwP + (size_t)b * KS * 2048 + (size_t)lane * 8;

    // mask-expansion LUT: nibble -> two dwords of 16-bit AND masks
    if (t < 16)
        lutm[t] = make_uint2(((t & 1) ? 0xFFFFu : 0u) | ((t & 2) ? 0xFFFF0000u : 0u),
                             ((t & 4) ? 0xFFFFu : 0u) | ((t & 8) ? 0xFFFF0000u : 0u));

    // stage er/rc for batch b: straight float4 copies (transforms already
    // done in k_prep), 1024 float4 each, conflict-free
    {
        const float4* es = (const float4*)(ERt + (size_t)b * NN);
        const float4* cs = (const float4*)(RCt + (size_t)b * NN);
        float4* ed = (float4*)REs_er;
        float4* cd = (float4*)REs_rc;
        #pragma unroll
        for (int k = 0; k < 4; ++k) {
            ed[t + k * 256] = es[t + k * 256];
            cd[t + k * 256] = cs[t + k * 256];
        }
    }
    __syncthreads();

    f32x4 acca[4], accb[4];
    f32x4 sacca = (f32x4)0.f, saccb = (f32x4)0.f;
    #pragma unroll
    for (int ct = 0; ct < 4; ++ct) { acca[ct] = (f32x4)0.f; accb[ct] = (f32x4)0.f; }
    half8 vones;
    #pragma unroll
    for (int k = 0; k < 8; ++k) vones[k] = (_Float16)1.0f;

    const int ks0 = wv * NKW;            // this wave's 32 K-steps

    // prefetch step 0: VMEM (XwP fragments + mask words)
    const _Float16* base = xp + (size_t)ks0 * 2048;
    half8 nb0 = *(const half8*)(base + 0 * 512);
    half8 nb1 = *(const half8*)(base + 1 * 512);
    half8 nb2 = *(const half8*)(base + 2 * 512);
    half8 nb3 = *(const half8*)(base + 3 * 512);
    unsigned int nwa = bitsT[(size_t)ks0 * NN + rowa];
    unsigned int nwb = bitsT[(size_t)ks0 * NN + rowb];
    // prefetch step 0: LDS (er/rc pairs) into registers
    float4 pe0 = *(const float4*)(REs_er + ks0 * 32 + q * 8);
    float4 pe1 = *(const float4*)(REs_er + ks0 * 32 + q * 8 + 4);
    float4 pc0 = *(const float4*)(REs_rc + ks0 * 32 + q * 8);
    float4 pc1 = *(const float4*)(REs_rc + ks0 * 32 + q * 8 + 4);

    #pragma unroll 4
    for (int kk = 0; kk < NKW; ++kk) {
        half8 bf0 = nb0, bf1 = nb1, bf2 = nb2, bf3 = nb3;
        float4 e0v = pe0, e1v = pe1, c0v = pc0, c1v = pc1;
        unsigned int wax = nwa >> (q * 8);
        unsigned int wbx = nwb >> (q * 8);
        uint2 ma0 = lutm[wax & 15], ma1 = lutm[(wax >> 4) & 15];
        uint2 mb0 = lutm[wbx & 15], mb1 = lutm[(wbx >> 4) & 15];

        // prefetch next step (clamped re-read on the last iteration):
        // VMEM (XwP + bitsT) and LDS (er/rc) both 1-deep
        {
            int nk = kk + 1 < NKW ? kk + 1 : kk;
            const _Float16* nbase = xp + (size_t)(ks0 + nk) * 2048;
            nb0 = *(const half8*)(nbase + 0 * 512);
            nb1 = *(const half8*)(nbase + 1 * 512);
            nb2 = *(const half8*)(nbase + 2 * 512);
            nb3 = *(const half8*)(nbase + 3 * 512);
            nwa = bitsT[(size_t)(ks0 + nk) * NN + rowa];
            nwb = bitsT[(size_t)(ks0 + nk) * NN + rowb];
            pe0 = *(const float4*)(REs_er + (ks0 + nk) * 32 + q * 8);
            pe1 = *(const float4*)(REs_er + (ks0 + nk) * 32 + q * 8 + 4);
            pc0 = *(const float4*)(REs_rc + (ks0 + nk) * 32 + q * 8);
            pc1 = *(const float4*)(REs_rc + (ks0 + nk) * 32 + q * 8 + 4);
        }

        float er8[8] = {e0v.x, e0v.y, e0v.z, e0v.w, e1v.x, e1v.y, e1v.z, e1v.w};
        float rc8[8] = {c0v.x, c0v.y, c0v.z, c0v.w, c1v.x, c1v.y, c1v.z, c1v.w};

        // p = max(el*er_j, lc + rc_j); pack f16 (RTZ); AND-mask via LUT
        float pa[8], pb[8];
        #pragma unroll
        for (int jj = 0; jj < 8; ++jj)
            pa[jj] = fmaxf(lea.y * er8[jj], lea.x + rc8[jj]);
        #pragma unroll
        for (int jj = 0; jj < 8; ++jj)
            pb[jj] = fmaxf(leb.y * er8[jj], leb.x + rc8[jj]);

        uint4 ua, ub;
        ua.x = __builtin_bit_cast(unsigned int, __builtin_amdgcn_cvt_pkrtz(pa[0], pa[1])) & ma0.x;
        ua.y = __builtin_bit_cast(unsigned int, __builtin_amdgcn_cvt_pkrtz(pa[2], pa[3])) & ma0.y;
        ua.z = __builtin_bit_cast(unsigned int, __builtin_amdgcn_cvt_pkrtz(pa[4], pa[5])) & ma1.x;
        ua.w = __builtin_bit_cast(unsigned int, __builtin_amdgcn_cvt_pkrtz(pa[6], pa[7])) & ma1.y;
        ub.x = __builtin_bit_cast(unsigned int, __builtin_amdgcn_cvt_pkrtz(pb[0], pb[1])) & mb0.x;
        ub.y = __builtin_bit_cast(unsigned int, __builtin_amdgcn_cvt_pkrtz(pb[2], pb[3])) & mb0.y;
        ub.z = __builtin_bit_cast(unsigned int, __builtin_amdgcn_cvt_pkrtz(pb[4], pb[5])) & mb1.x;
        ub.w = __builtin_bit_cast(unsigned int, __builtin_amdgcn_cvt_pkrtz(pb[6], pb[7])) & mb1.y;
        half8 a0a = __builtin_bit_cast(half8, ua);
        half8 a0b = __builtin_bit_cast(half8, ub);

        __builtin_amdgcn_s_setprio(1);
        acca[0] = __builtin_amdgcn_mfma_f32_16x16x32_f16(a0a, bf0, acca[0], 0, 0, 0);
        acca[1] = __builtin_amdgcn_mfma_f32_16x16x32_f16(a0a, bf1, acca[1], 0, 0, 0);
        acca[2] = __builtin_amdgcn_mfma_f32_16x16x32_f16(a0a, bf2, acca[2], 0, 0, 0);
        acca[3] = __builtin_amdgcn_mfma_f32_16x16x32_f16(a0a, bf3, acca[3], 0, 0, 0);
        sacca   = __builtin_amdgcn_mfma_f32_16x16x32_f16(a0a, vones, sacca, 0, 0, 0);

        accb[0] = __builtin_amdgcn_mfma_f32_16x16x32_f16(a0b, bf0, accb[0], 0, 0, 0);
        accb[1] = __builtin_amdgcn_mfma_f32_16x16x32_f16(a0b, bf1, accb[1], 0, 0, 0);
        accb[2] = __builtin_amdgcn_mfma_f32_16x16x32_f16(a0b, bf2, accb[2], 0, 0, 0);
        accb[3] = __builtin_amdgcn_mfma_f32_16x16x32_f16(a0b, bf3, accb[3], 0, 0, 0);
        saccb   = __builtin_amdgcn_mfma_f32_16x16x32_f16(a0b, vones, saccb, 0, 0, 0);
        __builtin_amdgcn_s_setprio(0);
    }

    __syncthreads();   // all waves done reading REs before Lacc overlays it

    // stage 1: waves 2,3 dump  (D[row = q*4+r][col = lm] per 16x16 tile)
    if (wv >= 2) {
        #pragma unroll
        for (int r = 0; r < 4; ++r) {
            int lrow = q * 4 + r;
            #pragma unroll
            for (int ct = 0; ct < 4; ++ct) {
                Lacc[wv - 2][lrow][ct * 16 + lm]      = acca[ct][r];
                Lacc[wv - 2][16 + lrow][ct * 16 + lm] = accb[ct][r];
            }
            if (lm == 0) {
                Lsum[(wv - 2) * 32 + lrow]      = sacca[r];
                Lsum[(wv - 2) * 32 + 16 + lrow] = saccb[r];
            }
        }
    }
    __syncthreads();
    // stage 2: waves 0,1 absorb + dump
    if (wv < 2) {
        #pragma unroll
        for (int r = 0; r < 4; ++r) {
            int lrow = q * 4 + r;
            #pragma unroll
            for (int ct = 0; ct < 4; ++ct) {
                Lacc[wv][lrow][ct * 16 + lm]      += acca[ct][r];
                Lacc[wv][16 + lrow][ct * 16 + lm] += accb[ct][r];
            }
            if (lm == 0) {
                Lsum[wv * 32 + lrow]      += sacca[r];
                Lsum[wv * 32 + 16 + lrow] += saccb[r];
            }
        }
    }
    __syncthreads();
    // stage 3: combine the 2 buffers, normalize, final coalesced write (32 rows)
    #pragma unroll
    for (int it = 0; it < 2; ++it) {
        int idx  = t + it * 256;
        int lrow = idx >> 4;            // 0..31
        int c0   = (idx & 15) * 4;      // 0..60
        float s = Lsum[lrow] + Lsum[32 + lrow];
        float inv = 1.f / s;
        float4 o;
        o.x = (Lacc[0][lrow][c0 + 0] + Lacc[1][lrow][c0 + 0]) * inv;
        o.y = (Lacc[0][lrow][c0 + 1] + Lacc[1][lrow][c0 + 1]) * inv;
        o.z = (Lacc[0][lrow][c0 + 2] + Lacc[1][lrow][c0 + 2]) * inv;
        o.w = (Lacc[0][lrow][c0 + 3] + Lacc[1][lrow][c0 + 3]) * inv;
        *(float4*)&out[((size_t)(b * NN + i0 + lrow) << 6) + c0] = o;
    }
}

// ---------------------------------------------------------------------------
extern "C" void kernel_launch(void* const* d_in, const int* in_sizes, int n_in,
                              void* d_out, int out_size, void* d_ws, size_t ws_size,
                              hipStream_t stream) {
    const float* X    = (const float*)d_in[0];
    const int*   A    = (const int*)d_in[1];
    const float* W    = (const float*)d_in[2];
    const float* avec = (const float*)d_in[3];
    float* out = (float*)d_out;

    char* ws = (char*)d_ws;
    size_t off = 0;
    _Float16* XwP = (_Float16*)(ws + off); off += (size_t)BB * NN * FF * 2;  // 2 MB
    float2* LE = (float2*)(ws + off);      off += (size_t)BB * NN * 8;       // 128 KB
    float* ERt = (float*)(ws + off);       off += (size_t)BB * NN * 4;       // 64 KB
    float* RCt = (float*)(ws + off);       off += (size_t)BB * NN * 4;       // 64 KB
    unsigned int* bitsT = (unsigned int*)(ws + off);
    off += (size_t)KS * NN * 4;                                              // 2 MB
    (void)off; (void)ws_size;

    // fused pre + pack: pre blocks first (co-resident with the pack flood)
    k_prep<<<PREB + NN * NN / 1024, 256, 0, stream>>>(X, W, avec, A, XwP, LE, ERt, RCt, bitsT);
    k_main<<<dim3(NN / 32, BB), 256, 0, stream>>>(XwP, LE, ERt, RCt, bitsT, out);
}